// Round 2
// baseline (361.904 us; speedup 1.0000x reference)
//
#include <hip/hip_runtime.h>

#define NN 50000
#define NE 800000
#define NF 64
#define NH 64
#define NC 16

// ---------------------------------------------------------------------------
// Workspace layout (ints): deg[NN] | off[NN+1] | cur[NN] | csr_src[NE]
// ~3.8 MB total. Only deg needs zeroing each launch; everything else is
// fully written before being read (harness poisons ws with 0xAA).
// ---------------------------------------------------------------------------

// Kernel 1: degree histogram. 800K int atomics (vs 51.2M fp32 atomics in the
// old scatter design) -- the whole point of the CSR rebuild.
__global__ __launch_bounds__(256) void hist_kernel(
    const int* __restrict__ dst, int* __restrict__ deg, int n_edges) {
    int i = blockIdx.x * blockDim.x + threadIdx.x;
    int stride = gridDim.x * blockDim.x;
    for (int e = i; e < n_edges; e += stride) atomicAdd(&deg[dst[e]], 1);
}

// Kernel 2: exclusive scan of deg -> off (and cur copy). Single block.
// chunk-serial sums -> Hillis-Steele over 1024 partials -> chunk write-back.
#define SCAN_T 1024
__global__ __launch_bounds__(SCAN_T) void scan_kernel(
    const int* __restrict__ deg, int* __restrict__ off,
    int* __restrict__ cur, int n) {
    __shared__ int part[SCAN_T];
    int t = threadIdx.x;
    int chunk = (n + SCAN_T - 1) / SCAN_T;           // 49 for n=50000
    int lo = t * chunk;
    int hi = lo + chunk; if (hi > n) hi = n; if (lo > n) lo = n;
    int s = 0;
    for (int i = lo; i < hi; ++i) s += deg[i];
    part[t] = s;
    __syncthreads();
    for (int d = 1; d < SCAN_T; d <<= 1) {           // inclusive scan
        int v = (t >= d) ? part[t - d] : 0;
        __syncthreads();
        part[t] += v;
        __syncthreads();
    }
    int run = (t == 0) ? 0 : part[t - 1];            // exclusive base
    for (int i = lo; i < hi; ++i) {
        off[i] = run; cur[i] = run;
        run += deg[i];
    }
    if (t == 0) off[n] = part[SCAN_T - 1];           // total = n_edges
}

// Kernel 3: scatter src ids into CSR slots. 800K int atomics + 4B writes.
__global__ __launch_bounds__(256) void scatter_kernel(
    const int* __restrict__ src, const int* __restrict__ dst,
    int* __restrict__ cur, int* __restrict__ csr_src, int n_edges) {
    int i = blockIdx.x * blockDim.x + threadIdx.x;
    int stride = gridDim.x * blockDim.x;
    for (int e = i; e < n_edges; e += stride) {
        int slot = atomicAdd(&cur[dst[e]], 1);
        csr_src[slot] = src[e];
    }
}

// Kernel 4: fused gather + mean + dual GEMM + relu + classifier.
// 16 nodes / 256-thread block (4 waves x 4 sequential nodes). Wave w, lane j:
// gather h_neigh[j] of its node in-register (each neighbor row = one
// coalesced 256B read), stage x/hn rows in LDS, dense k-loop against
// LDS-staged weights (39.25KB LDS -> 4 blocks/CU). h_neigh never touches
// global memory. Classifier: 4 lane-groups x 16 classes + shfl_xor reduce.
__global__ __launch_bounds__(256) void sage_fused_kernel(
    const float* __restrict__ x,
    const int* __restrict__ off,
    const int* __restrict__ csr_src,
    const float* __restrict__ Wself,
    const float* __restrict__ Wneigh,
    const float* __restrict__ bsage,
    const float* __restrict__ Wfc,
    const float* __restrict__ bfc,
    float* __restrict__ out,
    int n_nodes) {
    __shared__ float sWs[NF * NH];   // 16 KB
    __shared__ float sWn[NF * NH];   // 16 KB
    __shared__ float sWf[NH * NC];   // 4 KB
    __shared__ float sx[4][NF];
    __shared__ float sn[4][NF];
    __shared__ float sh[4][NH];

    int tid = threadIdx.x;
    for (int i = tid; i < NF * NH; i += 256) {
        sWs[i] = Wself[i];
        sWn[i] = Wneigh[i];
    }
    for (int i = tid; i < NH * NC; i += 256) sWf[i] = Wfc[i];

    int w = tid >> 6;        // wave 0..3
    int j = tid & 63;        // feature lane
    float bj = bsage[j];
    __syncthreads();

    for (int iter = 0; iter < 4; ++iter) {
        int node = blockIdx.x * 16 + iter * 4 + w;
        float xv = 0.f, nv = 0.f;
        if (node < n_nodes) {
            int o0 = off[node], o1 = off[node + 1];
            float acc = 0.f;
            int i = o0;
            for (; i + 4 <= o1; i += 4) {           // unroll-4: overlap row loads
                int s0 = csr_src[i], s1 = csr_src[i + 1];
                int s2 = csr_src[i + 2], s3 = csr_src[i + 3];
                acc += x[s0 * NF + j];
                acc += x[s1 * NF + j];
                acc += x[s2 * NF + j];
                acc += x[s3 * NF + j];
            }
            for (; i < o1; ++i) acc += x[csr_src[i] * NF + j];
            int d = o1 - o0;
            nv = acc / (float)(d > 1 ? d : 1);
            xv = x[node * NF + j];
        }
        sx[w][j] = xv;
        sn[w][j] = nv;
        __syncthreads();

        // hidden j = relu(sum_k x[k]*Ws[k][j] + hn[k]*Wn[k][j] + b[j])
        // sx[w][k]: wave-broadcast (free). sWs[k*64+j]: banks j%32, 2-way (free).
        float acc = bj;
#pragma unroll
        for (int k = 0; k < NF; ++k) {
            acc = fmaf(sx[w][k], sWs[k * NH + j], acc);
            acc = fmaf(sn[w][k], sWn[k * NH + j], acc);
        }
        acc = fmaxf(acc, 0.f);
        sh[w][j] = acc;
        __syncthreads();

        // classifier: lane = g*16+c; partial over k in [16g,16g+16), xor-reduce
        int g = j >> 4, c = j & 15;
        float o = 0.f;
#pragma unroll
        for (int k = 0; k < 16; ++k)
            o = fmaf(sh[w][g * 16 + k], sWf[(g * 16 + k) * NC + c], o);
        o += __shfl_xor(o, 16);
        o += __shfl_xor(o, 32);
        if (node < n_nodes && g == 0) out[node * NC + c] = o + bfc[c];
        __syncthreads();   // protect sx/sn/sh before next iteration
    }
}

extern "C" void kernel_launch(void* const* d_in, const int* in_sizes, int n_in,
                              void* d_out, int out_size, void* d_ws, size_t ws_size,
                              hipStream_t stream) {
    const float* x      = (const float*)d_in[0];
    const int*   src    = (const int*)d_in[1];
    const int*   dst    = (const int*)d_in[2];
    const float* Wself  = (const float*)d_in[3];
    const float* Wneigh = (const float*)d_in[4];
    const float* bsage  = (const float*)d_in[5];
    const float* Wfc    = (const float*)d_in[6];
    const float* bfc    = (const float*)d_in[7];
    float* out = (float*)d_out;

    int n_nodes = in_sizes[0] / NF;
    int n_edges = in_sizes[1];

    int* deg     = (int*)d_ws;
    int* off     = deg + n_nodes;
    int* cur     = off + n_nodes + 1;
    int* csr_src = cur + n_nodes;

    hipMemsetAsync(deg, 0, (size_t)n_nodes * sizeof(int), stream);

    hist_kernel<<<2048, 256, 0, stream>>>(dst, deg, n_edges);
    scan_kernel<<<1, SCAN_T, 0, stream>>>(deg, off, cur, n_nodes);
    scatter_kernel<<<2048, 256, 0, stream>>>(src, dst, cur, csr_src, n_edges);

    int fused_blocks = (n_nodes + 15) / 16;
    sage_fused_kernel<<<fused_blocks, 256, 0, stream>>>(
        x, off, csr_src, Wself, Wneigh, bsage, Wfc, bfc, out, n_nodes);
}

// Round 3
// 263.215 us; speedup vs baseline: 1.3749x; 1.3749x over previous
//
#include <hip/hip_runtime.h>

#define NN 50000
#define NE 800000
#define NF 64
#define NH 64
#define NC 16

// Workspace (ints): deg[NN] | off[NN+1] | cur[NN] | bsum[64] | bbase[64] | csr_src[NE]

// ---------------------------------------------------------------------------
// Kernel 1: degree histogram. 800K int atomics on L2-resident 200KB deg.
// ---------------------------------------------------------------------------
__global__ __launch_bounds__(256) void hist_kernel(
    const int* __restrict__ dst, int* __restrict__ deg, int n_edges) {
    int i = blockIdx.x * blockDim.x + threadIdx.x;
    int stride = gridDim.x * blockDim.x;
    for (int e = i; e < n_edges; e += stride) atomicAdd(&deg[dst[e]], 1);
}

// ---------------------------------------------------------------------------
// Hierarchical scan (replaces the 110us single-block scan: it was 1-CU,
// latency-bound, 64-lines-per-load uncoalesced. All 3 stages below are
// coalesced int4 + multi-block).
// Stage A: per-block (1024 elems) sums.
// ---------------------------------------------------------------------------
#define SCAN_BLK 1024
__global__ __launch_bounds__(256) void scan_partial_kernel(
    const int* __restrict__ deg, int* __restrict__ bsum, int n) {
    __shared__ int red[256];
    int t = threadIdx.x;
    int base = blockIdx.x * SCAN_BLK + t * 4;
    int s = 0;
    if (base + 3 < n) {
        int4 v = *(const int4*)(deg + base);
        s = v.x + v.y + v.z + v.w;
    } else {
        for (int i = 0; i < 4; ++i) if (base + i < n) s += deg[base + i];
    }
    red[t] = s;
    __syncthreads();
    for (int d = 128; d > 0; d >>= 1) {
        if (t < d) red[t] += red[t + d];
        __syncthreads();
    }
    if (t == 0) bsum[blockIdx.x] = red[0];
}

// Stage B: one wave scans the <=64 block sums -> exclusive bases; off[n]=total.
__global__ __launch_bounds__(64) void scan_base_kernel(
    const int* __restrict__ bsum, int* __restrict__ bbase,
    int* __restrict__ off, int nb, int n) {
    int t = threadIdx.x;
    int v = (t < nb) ? bsum[t] : 0;
    int inc = v;
#pragma unroll
    for (int d = 1; d < 64; d <<= 1) {
        int u = __shfl_up(inc, d);
        if (t >= d) inc += u;
    }
    if (t < nb) bbase[t] = inc - v;     // exclusive base
    if (t == nb - 1) off[n] = inc;      // grand total (= n_edges)
}

// Stage C: re-read chunk, in-block exclusive scan, add base, write off & cur.
__global__ __launch_bounds__(256) void scan_write_kernel(
    const int* __restrict__ deg, const int* __restrict__ bbase,
    int* __restrict__ off, int* __restrict__ cur, int n) {
    __shared__ int tsum[256];
    int t = threadIdx.x;
    int base = blockIdx.x * SCAN_BLK + t * 4;
    int v[4];
    int s = 0;
#pragma unroll
    for (int i = 0; i < 4; ++i) {
        v[i] = (base + i < n) ? deg[base + i] : 0;
        s += v[i];
    }
    tsum[t] = s;
    __syncthreads();
    // Hillis-Steele inclusive scan over 256 thread-sums
    for (int d = 1; d < 256; d <<= 1) {
        int u = (t >= d) ? tsum[t - d] : 0;
        __syncthreads();
        tsum[t] += u;
        __syncthreads();
    }
    int run = tsum[t] - s + bbase[blockIdx.x];   // exclusive thread base
#pragma unroll
    for (int i = 0; i < 4; ++i) {
        if (base + i < n) { off[base + i] = run; cur[base + i] = run; }
        run += v[i];
    }
}

// ---------------------------------------------------------------------------
// Kernel 3: scatter src ids into CSR slots.
// ---------------------------------------------------------------------------
__global__ __launch_bounds__(256) void scatter_kernel(
    const int* __restrict__ src, const int* __restrict__ dst,
    int* __restrict__ cur, int* __restrict__ csr_src, int n_edges) {
    int i = blockIdx.x * blockDim.x + threadIdx.x;
    int stride = gridDim.x * blockDim.x;
    for (int e = i; e < n_edges; e += stride) {
        int slot = atomicAdd(&cur[dst[e]], 1);
        csr_src[slot] = src[e];
    }
}

// ---------------------------------------------------------------------------
// Kernel 4: fused gather + mean + dual GEMM + relu + classifier (unchanged).
// ---------------------------------------------------------------------------
__global__ __launch_bounds__(256) void sage_fused_kernel(
    const float* __restrict__ x,
    const int* __restrict__ off,
    const int* __restrict__ csr_src,
    const float* __restrict__ Wself,
    const float* __restrict__ Wneigh,
    const float* __restrict__ bsage,
    const float* __restrict__ Wfc,
    const float* __restrict__ bfc,
    float* __restrict__ out,
    int n_nodes) {
    __shared__ float sWs[NF * NH];
    __shared__ float sWn[NF * NH];
    __shared__ float sWf[NH * NC];
    __shared__ float sx[4][NF];
    __shared__ float sn[4][NF];
    __shared__ float sh[4][NH];

    int tid = threadIdx.x;
    for (int i = tid; i < NF * NH; i += 256) {
        sWs[i] = Wself[i];
        sWn[i] = Wneigh[i];
    }
    for (int i = tid; i < NH * NC; i += 256) sWf[i] = Wfc[i];

    int w = tid >> 6;
    int j = tid & 63;
    float bj = bsage[j];
    __syncthreads();

    for (int iter = 0; iter < 4; ++iter) {
        int node = blockIdx.x * 16 + iter * 4 + w;
        float xv = 0.f, nv = 0.f;
        if (node < n_nodes) {
            int o0 = off[node], o1 = off[node + 1];
            float acc = 0.f;
            int i = o0;
            for (; i + 4 <= o1; i += 4) {
                int s0 = csr_src[i], s1 = csr_src[i + 1];
                int s2 = csr_src[i + 2], s3 = csr_src[i + 3];
                acc += x[s0 * NF + j];
                acc += x[s1 * NF + j];
                acc += x[s2 * NF + j];
                acc += x[s3 * NF + j];
            }
            for (; i < o1; ++i) acc += x[csr_src[i] * NF + j];
            int d = o1 - o0;
            nv = acc / (float)(d > 1 ? d : 1);
            xv = x[node * NF + j];
        }
        sx[w][j] = xv;
        sn[w][j] = nv;
        __syncthreads();

        float acc = bj;
#pragma unroll
        for (int k = 0; k < NF; ++k) {
            acc = fmaf(sx[w][k], sWs[k * NH + j], acc);
            acc = fmaf(sn[w][k], sWn[k * NH + j], acc);
        }
        acc = fmaxf(acc, 0.f);
        sh[w][j] = acc;
        __syncthreads();

        int g = j >> 4, c = j & 15;
        float o = 0.f;
#pragma unroll
        for (int k = 0; k < 16; ++k)
            o = fmaf(sh[w][g * 16 + k], sWf[(g * 16 + k) * NC + c], o);
        o += __shfl_xor(o, 16);
        o += __shfl_xor(o, 32);
        if (node < n_nodes && g == 0) out[node * NC + c] = o + bfc[c];
        __syncthreads();
    }
}

extern "C" void kernel_launch(void* const* d_in, const int* in_sizes, int n_in,
                              void* d_out, int out_size, void* d_ws, size_t ws_size,
                              hipStream_t stream) {
    const float* x      = (const float*)d_in[0];
    const int*   src    = (const int*)d_in[1];
    const int*   dst    = (const int*)d_in[2];
    const float* Wself  = (const float*)d_in[3];
    const float* Wneigh = (const float*)d_in[4];
    const float* bsage  = (const float*)d_in[5];
    const float* Wfc    = (const float*)d_in[6];
    const float* bfc    = (const float*)d_in[7];
    float* out = (float*)d_out;

    int n_nodes = in_sizes[0] / NF;
    int n_edges = in_sizes[1];

    int* deg     = (int*)d_ws;
    int* off     = deg + n_nodes;
    int* cur     = off + n_nodes + 1;
    int* bsum    = cur + n_nodes;
    int* bbase   = bsum + 64;
    int* csr_src = bbase + 64;

    int nb = (n_nodes + SCAN_BLK - 1) / SCAN_BLK;   // 49

    hipMemsetAsync(deg, 0, (size_t)n_nodes * sizeof(int), stream);

    hist_kernel<<<2048, 256, 0, stream>>>(dst, deg, n_edges);
    scan_partial_kernel<<<nb, 256, 0, stream>>>(deg, bsum, n_nodes);
    scan_base_kernel<<<1, 64, 0, stream>>>(bsum, bbase, off, nb, n_nodes);
    scan_write_kernel<<<nb, 256, 0, stream>>>(deg, bbase, off, cur, n_nodes);
    scatter_kernel<<<2048, 256, 0, stream>>>(src, dst, cur, csr_src, n_edges);

    int fused_blocks = (n_nodes + 15) / 16;
    sage_fused_kernel<<<fused_blocks, 256, 0, stream>>>(
        x, off, csr_src, Wself, Wneigh, bsage, Wfc, bfc, out, n_nodes);
}

// Round 5
// 233.973 us; speedup vs baseline: 1.5468x; 1.1250x over previous
//
#include <hip/hip_runtime.h>

#define NN 50000
#define NE 800000
#define NF 64
#define NH 64
#define NC 16

// Workspace: ints  deg[NN] | off[NN+1] | cur[NN] | bsum[64] | bbase[64] | csr_src[NE]
//            float hn[NN*NF]   (mean-aggregated neighbor features)

// ---------------------------------------------------------------------------
// Kernel 1: degree histogram, int4-vectorized edge reads.
// ---------------------------------------------------------------------------
__global__ __launch_bounds__(256) void hist_kernel(
    const int* __restrict__ dst, int* __restrict__ deg, int n_edges) {
    int i = blockIdx.x * blockDim.x + threadIdx.x;
    int stride = gridDim.x * blockDim.x;
    int n4 = n_edges >> 2;
    const int4* dst4 = (const int4*)dst;
    for (int e = i; e < n4; e += stride) {
        int4 v = dst4[e];
        atomicAdd(&deg[v.x], 1);
        atomicAdd(&deg[v.y], 1);
        atomicAdd(&deg[v.z], 1);
        atomicAdd(&deg[v.w], 1);
    }
    int tail = n4 * 4 + i;
    if (tail < n_edges) atomicAdd(&deg[dst[tail]], 1);
}

// ---------------------------------------------------------------------------
// Hierarchical scan (3 stages, all coalesced + multi-CU).
// ---------------------------------------------------------------------------
#define SCAN_BLK 1024
__global__ __launch_bounds__(256) void scan_partial_kernel(
    const int* __restrict__ deg, int* __restrict__ bsum, int n) {
    __shared__ int red[256];
    int t = threadIdx.x;
    int base = blockIdx.x * SCAN_BLK + t * 4;
    int s = 0;
    if (base + 3 < n) {
        int4 v = *(const int4*)(deg + base);
        s = v.x + v.y + v.z + v.w;
    } else {
        for (int i = 0; i < 4; ++i) if (base + i < n) s += deg[base + i];
    }
    red[t] = s;
    __syncthreads();
    for (int d = 128; d > 0; d >>= 1) {
        if (t < d) red[t] += red[t + d];
        __syncthreads();
    }
    if (t == 0) bsum[blockIdx.x] = red[0];
}

__global__ __launch_bounds__(64) void scan_base_kernel(
    const int* __restrict__ bsum, int* __restrict__ bbase,
    int* __restrict__ off, int nb, int n) {
    int t = threadIdx.x;
    int v = (t < nb) ? bsum[t] : 0;
    int inc = v;
#pragma unroll
    for (int d = 1; d < 64; d <<= 1) {
        int u = __shfl_up(inc, d);
        if (t >= d) inc += u;
    }
    if (t < nb) bbase[t] = inc - v;
    if (t == nb - 1) off[n] = inc;
}

__global__ __launch_bounds__(256) void scan_write_kernel(
    const int* __restrict__ deg, const int* __restrict__ bbase,
    int* __restrict__ off, int* __restrict__ cur, int n) {
    __shared__ int tsum[256];
    int t = threadIdx.x;
    int base = blockIdx.x * SCAN_BLK + t * 4;
    int v[4];
    int s = 0;
#pragma unroll
    for (int i = 0; i < 4; ++i) {
        v[i] = (base + i < n) ? deg[base + i] : 0;
        s += v[i];
    }
    tsum[t] = s;
    __syncthreads();
    for (int d = 1; d < 256; d <<= 1) {
        int u = (t >= d) ? tsum[t - d] : 0;
        __syncthreads();
        tsum[t] += u;
        __syncthreads();
    }
    int run = tsum[t] - s + bbase[blockIdx.x];
#pragma unroll
    for (int i = 0; i < 4; ++i) {
        if (base + i < n) { off[base + i] = run; cur[base + i] = run; }
        run += v[i];
    }
}

// ---------------------------------------------------------------------------
// Kernel 3: scatter src ids into CSR slots (int4 edge reads).
// ---------------------------------------------------------------------------
__global__ __launch_bounds__(256) void scatter_kernel(
    const int* __restrict__ src, const int* __restrict__ dst,
    int* __restrict__ cur, int* __restrict__ csr_src, int n_edges) {
    int i = blockIdx.x * blockDim.x + threadIdx.x;
    int stride = gridDim.x * blockDim.x;
    int n4 = n_edges >> 2;
    const int4* dst4 = (const int4*)dst;
    const int4* src4 = (const int4*)src;
    for (int e = i; e < n4; e += stride) {
        int4 d = dst4[e];
        int4 s = src4[e];
        csr_src[atomicAdd(&cur[d.x], 1)] = s.x;
        csr_src[atomicAdd(&cur[d.y], 1)] = s.y;
        csr_src[atomicAdd(&cur[d.z], 1)] = s.z;
        csr_src[atomicAdd(&cur[d.w], 1)] = s.w;
    }
    int tail = n4 * 4 + i;
    if (tail < n_edges) csr_src[atomicAdd(&cur[dst[tail]], 1)] = src[tail];
}

// ---------------------------------------------------------------------------
// Kernel 4: gather + mean only. One wave per node, lane j = feature j.
// No LDS, low VGPR -> high occupancy; 8 accumulators keep 8 coalesced 256B
// row-loads in flight per wave. Neighbor ids: one coalesced 64-wide load per
// 64 neighbors, then __shfl broadcast.
// ---------------------------------------------------------------------------
__global__ __launch_bounds__(256) void agg_kernel(
    const float* __restrict__ x,
    const int* __restrict__ off,
    const int* __restrict__ csr_src,
    float* __restrict__ hn,
    int n_nodes) {
    int w = threadIdx.x >> 6, j = threadIdx.x & 63;
    int node = blockIdx.x * 4 + w;
    if (node >= n_nodes) return;
    int o0 = off[node], o1 = off[node + 1];
    float a0 = 0, a1 = 0, a2 = 0, a3 = 0, a4 = 0, a5 = 0, a6 = 0, a7 = 0;
    for (int base = o0; base < o1; base += 64) {
        int cnt = o1 - base; if (cnt > 64) cnt = 64;
        int idx = (base + j < o1) ? csr_src[base + j] : 0;
        int k = 0;
        for (; k + 8 <= cnt; k += 8) {
            int s0 = __shfl(idx, k + 0), s1 = __shfl(idx, k + 1);
            int s2 = __shfl(idx, k + 2), s3 = __shfl(idx, k + 3);
            int s4 = __shfl(idx, k + 4), s5 = __shfl(idx, k + 5);
            int s6 = __shfl(idx, k + 6), s7 = __shfl(idx, k + 7);
            a0 += x[s0 * NF + j];
            a1 += x[s1 * NF + j];
            a2 += x[s2 * NF + j];
            a3 += x[s3 * NF + j];
            a4 += x[s4 * NF + j];
            a5 += x[s5 * NF + j];
            a6 += x[s6 * NF + j];
            a7 += x[s7 * NF + j];
        }
        for (; k < cnt; ++k) {
            int s = __shfl(idx, k);
            a0 += x[s * NF + j];
        }
    }
    float acc = ((a0 + a1) + (a2 + a3)) + ((a4 + a5) + (a6 + a7));
    int d = o1 - o0;
    hn[node * NF + j] = acc / (float)(d > 1 ? d : 1);
}

// ---------------------------------------------------------------------------
// Kernel 5: dense MLP. 32 nodes/block (4 waves x 8 iters) amortizes the
// 36KB weight staging. sx/sn/sh rows are WAVE-PRIVATE -> no per-iter
// __syncthreads.
// ---------------------------------------------------------------------------
__global__ __launch_bounds__(256) void mlp_kernel(
    const float* __restrict__ x,
    const float* __restrict__ hn,
    const float* __restrict__ Wself,
    const float* __restrict__ Wneigh,
    const float* __restrict__ bsage,
    const float* __restrict__ Wfc,
    const float* __restrict__ bfc,
    float* __restrict__ out,
    int n_nodes) {
    __shared__ float sWs[NF * NH];
    __shared__ float sWn[NF * NH];
    __shared__ float sWf[NH * NC];
    __shared__ float sx[4][NF];
    __shared__ float sn[4][NF];
    __shared__ float sh[4][NH];

    int tid = threadIdx.x;
    for (int i = tid; i < NF * NH; i += 256) {
        sWs[i] = Wself[i];
        sWn[i] = Wneigh[i];
    }
    for (int i = tid; i < NH * NC; i += 256) sWf[i] = Wfc[i];

    int w = tid >> 6;
    int j = tid & 63;
    float bj = bsage[j];
    __syncthreads();   // weights visible to all waves; only barrier needed

    for (int it = 0; it < 8; ++it) {
        int node = blockIdx.x * 32 + it * 4 + w;
        float xv = 0.f, nv = 0.f;
        if (node < n_nodes) {
            xv = x[node * NF + j];
            nv = hn[node * NF + j];
        }
        sx[w][j] = xv;   // wave-private rows: compiler's lgkmcnt suffices
        sn[w][j] = nv;

        float acc = bj;
#pragma unroll
        for (int k = 0; k < NF; ++k) {
            acc = fmaf(sx[w][k], sWs[k * NH + j], acc);
            acc = fmaf(sn[w][k], sWn[k * NH + j], acc);
        }
        acc = fmaxf(acc, 0.f);
        sh[w][j] = acc;

        int g = j >> 4, c = j & 15;
        float o = 0.f;
#pragma unroll
        for (int k = 0; k < 16; ++k)
            o = fmaf(sh[w][g * 16 + k], sWf[(g * 16 + k) * NC + c], o);
        o += __shfl_xor(o, 16);
        o += __shfl_xor(o, 32);
        if (node < n_nodes && g == 0) out[node * NC + c] = o + bfc[c];
    }
}

extern "C" void kernel_launch(void* const* d_in, const int* in_sizes, int n_in,
                              void* d_out, int out_size, void* d_ws, size_t ws_size,
                              hipStream_t stream) {
    const float* x      = (const float*)d_in[0];
    const int*   src    = (const int*)d_in[1];
    const int*   dst    = (const int*)d_in[2];
    const float* Wself  = (const float*)d_in[3];
    const float* Wneigh = (const float*)d_in[4];
    const float* bsage  = (const float*)d_in[5];
    const float* Wfc    = (const float*)d_in[6];
    const float* bfc    = (const float*)d_in[7];
    float* out = (float*)d_out;

    int n_nodes = in_sizes[0] / NF;
    int n_edges = in_sizes[1];

    int* deg     = (int*)d_ws;
    int* off     = deg + n_nodes;
    int* cur     = off + n_nodes + 1;
    int* bsum    = cur + n_nodes;
    int* bbase   = bsum + 64;
    int* csr_src = bbase + 64;
    float* hn    = (float*)(csr_src + n_edges);

    int nb = (n_nodes + SCAN_BLK - 1) / SCAN_BLK;   // 49

    hipMemsetAsync(deg, 0, (size_t)n_nodes * sizeof(int), stream);

    int n4blocks = (n_edges / 4 + 255) / 256;       // 782
    hist_kernel<<<n4blocks, 256, 0, stream>>>(dst, deg, n_edges);
    scan_partial_kernel<<<nb, 256, 0, stream>>>(deg, bsum, n_nodes);
    scan_base_kernel<<<1, 64, 0, stream>>>(bsum, bbase, off, nb, n_nodes);
    scan_write_kernel<<<nb, 256, 0, stream>>>(deg, bbase, off, cur, n_nodes);
    scatter_kernel<<<n4blocks, 256, 0, stream>>>(src, dst, cur, csr_src, n_edges);

    agg_kernel<<<(n_nodes + 3) / 4, 256, 0, stream>>>(x, off, csr_src, hn, n_nodes);
    mlp_kernel<<<(n_nodes + 31) / 32, 256, 0, stream>>>(
        x, hn, Wself, Wneigh, bsage, Wfc, bfc, out, n_nodes);
}